// Round 10
// baseline (64.195 us; speedup 1.0000x reference)
//
#include <hip/hip_runtime.h>

// LengthRegulator: B=32, L=1024, D=512, T=max_len=4096
// out[b,t,:] = x[b, searchsorted(cumsum(dur[b]), t, 'right'), :], zero for t >= total.
//
// Kernel 1: per-row shfl scan ONLY -> cum (32 rows x 1024 ints, 128 KB in d_ws).
// Kernel 2: one-round balanced scatter (proven round-9 loop). Each of 2048
//           blocks stages its row's cum (4 KB, L2-broadcast) into LDS, binary-
//           searches its own 64 frame->token ids (prologue, ~1 us, concurrent
//           across the single block round), then streams 64 frames x 2 KB with
//           wave-uniform read dedup and NT stores. No idxmap pass at all.

#define B_ 32
#define L_ 1024
#define D_ 512
#define T_ 4096

typedef float fx4 __attribute__((ext_vector_type(4)));

// Kernel 1: per-row inclusive scan of durations -> cum. 32 blocks x 256 thr.
__global__ __launch_bounds__(256) void lr_scan(const int* __restrict__ dur,
                                               int* __restrict__ cumg) {
    __shared__ int wsum[4];
    const int b = blockIdx.x;
    const int tid = threadIdx.x;

    int4 dv = reinterpret_cast<const int4*>(dur + b * L_)[tid];
    const int a0 = max(dv.x, 0), a1 = max(dv.y, 0);
    const int a2 = max(dv.z, 0), a3 = max(dv.w, 0);
    const int tsum = a0 + a1 + a2 + a3;

    int v = tsum;
    const int lane = tid & 63;
    #pragma unroll
    for (int off = 1; off < 64; off <<= 1) {
        int n = __shfl_up(v, off, 64);
        if (lane >= off) v += n;
    }
    const int wv = tid >> 6;
    if (lane == 63) wsum[wv] = v;
    __syncthreads();
    int woff = 0;
    #pragma unroll
    for (int w = 0; w < 3; ++w)
        if (w < wv) woff += wsum[w];
    const int incl = v + woff;
    const int e = incl - tsum;

    int4 cv;
    cv.x = e + a0; cv.y = e + a0 + a1; cv.z = e + a0 + a1 + a2; cv.w = incl;
    reinterpret_cast<int4*>(cumg + b * L_)[tid] = cv;
}

// Kernel 2: 2048 blocks x 256 threads, one scheduling round, equal work.
// Block owns 64 consecutive frames of row b = blockIdx.x/64.
__global__ __launch_bounds__(256) void lr_scatter(const float* __restrict__ x,
                                                  const int* __restrict__ cumg,
                                                  float* __restrict__ out) {
    __shared__ int cum[L_];              // this row's cumulative sums (4 KB)
    __shared__ int ids[64];              // this block's 64 frame ids
    const int tid = threadIdx.x;
    const int b = blockIdx.x >> 6;       // 64 blocks per row
    const int f0 = (blockIdx.x & 63) * 64;

    // Stage cum row (coalesced int4 burst; L2-broadcast across 64 blocks/row).
    reinterpret_cast<int4*>(cum)[tid] =
        reinterpret_cast<const int4*>(cumg + b * L_)[tid];
    __syncthreads();

    // 64 threads resolve the block's frame ids (10-step LDS binary search).
    if (tid < 64) {
        const int t = f0 + tid;
        int idx = -1;                    // -1 => zero-pad frame
        if (t < cum[L_ - 1]) {
            idx = 0;                     // searchsorted(cum, t, 'right')
            #pragma unroll
            for (int s = 512; s > 0; s >>= 1)
                if (cum[idx + s - 1] <= t) idx += s;
        }
        ids[tid] = idx;
    }
    __syncthreads();

    // Main loop: identical to round 9 (proven). Wave-uniform dedup'd reads,
    // contiguous NT stores, pad frames write zeros.
    const int slot = tid & 127;          // float4 slot within frame
    const int fhalf = tid >> 7;          // 0: even frames, 1: odd frames

    const fx4* xb = reinterpret_cast<const fx4*>(x) + (size_t)b * (L_ * D_ / 4);
    fx4* o = reinterpret_cast<fx4*>(out);

    #pragma unroll
    for (int c = 0; c < 2; ++c) {
        const int chunk = blockIdx.x * 2 + c;         // 32-frame chunk
        fx4* ob = o + (size_t)chunk * 32 * 128;       // 32 frames x 128 slots

        int prev = -2;                                // != any id and != -1
        fx4 v = {0.f, 0.f, 0.f, 0.f};
        #pragma unroll
        for (int i2 = 0; i2 < 16; ++i2) {
            const int fi = 2 * i2 + fhalf;            // frame within chunk
            const int id = ids[c * 32 + fi];          // broadcast from LDS
            if (id != prev) {                         // wave-uniform branch
                if (id >= 0) v = xb[id * 128 + slot]; // token read (deduped)
                else         v = (fx4){0.f, 0.f, 0.f, 0.f};
                prev = id;
            }
            __builtin_nontemporal_store(v, &ob[fi * 128 + slot]);
        }
    }
}

extern "C" void kernel_launch(void* const* d_in, const int* in_sizes, int n_in,
                              void* d_out, int out_size, void* d_ws, size_t ws_size,
                              hipStream_t stream) {
    const float* x = (const float*)d_in[0];
    const int* dur = (const int*)d_in[1];
    // d_in[2] is max_len (== 4096), compile-time constant here.
    float* out = (float*)d_out;
    int* cumg = (int*)d_ws;              // B_*L_ ints = 128 KiB scratch

    lr_scan<<<B_, 256, 0, stream>>>(dur, cumg);
    lr_scatter<<<2048, 256, 0, stream>>>(x, cumg, out);
}

// Round 11
// 60.685 us; speedup vs baseline: 1.0578x; 1.0578x over previous
//
#include <hip/hip_runtime.h>

// LengthRegulator: B=32, L=1024, D=512, T=max_len=4096
// out[b,t,:] = x[b, searchsorted(cumsum(dur[b]), t, 'right'), :], zero for t >= total.
//
// SINGLE fused kernel, 2048 blocks x 256 threads (one scheduling round, 8/CU).
// Prologue (~1 us, amortized across co-resident blocks):
//   - read row's durations (4 KB int4 burst, L2-broadcast across 64 blocks/row)
//   - 256-thread x4 shfl scan (2 barriers) -> cum in LDS
//   - 64 threads binary-search the block's 64 frame->token ids
// Main loop (proven round-9 structure): 64 frames x 2 KB contiguous NT writes,
// wave-uniform read dedup (each token's vector read ~once), pad frames = zeros.

#define B_ 32
#define L_ 1024
#define D_ 512
#define T_ 4096

typedef float fx4 __attribute__((ext_vector_type(4)));

__global__ __launch_bounds__(256) void lr_fused(const float* __restrict__ x,
                                                const int* __restrict__ dur,
                                                float* __restrict__ out) {
    __shared__ int cum[L_];              // row cumulative sums (4 KB)
    __shared__ int wsum[4];
    __shared__ int ids[64];              // this block's 64 frame ids
    const int tid = threadIdx.x;
    const int b = blockIdx.x >> 6;       // 64 blocks per row
    const int f0 = (blockIdx.x & 63) * 64;

    // ---- prologue: scan this row's durations into cum (LDS) ----
    int4 dv = reinterpret_cast<const int4*>(dur + b * L_)[tid];
    const int a0 = max(dv.x, 0), a1 = max(dv.y, 0);
    const int a2 = max(dv.z, 0), a3 = max(dv.w, 0);
    const int tsum = a0 + a1 + a2 + a3;

    int v = tsum;
    const int lane = tid & 63;
    #pragma unroll
    for (int off = 1; off < 64; off <<= 1) {
        int n = __shfl_up(v, off, 64);
        if (lane >= off) v += n;
    }
    const int wv = tid >> 6;
    if (lane == 63) wsum[wv] = v;
    __syncthreads();
    int woff = 0;
    #pragma unroll
    for (int w = 0; w < 3; ++w)
        if (w < wv) woff += wsum[w];
    const int incl = v + woff;
    const int e = incl - tsum;
    cum[4 * tid + 0] = e + a0;
    cum[4 * tid + 1] = e + a0 + a1;
    cum[4 * tid + 2] = e + a0 + a1 + a2;
    cum[4 * tid + 3] = incl;
    __syncthreads();

    // ---- resolve this block's 64 frame ids (10-step LDS binary search) ----
    if (tid < 64) {
        const int t = f0 + tid;
        int idx = -1;                    // -1 => zero-pad frame
        if (t < cum[L_ - 1]) {
            idx = 0;                     // searchsorted(cum, t, 'right')
            #pragma unroll
            for (int s = 512; s > 0; s >>= 1)
                if (cum[idx + s - 1] <= t) idx += s;
        }
        ids[tid] = idx;
    }
    __syncthreads();

    // ---- main loop: proven round-9 structure ----
    const int slot = tid & 127;          // float4 slot within frame
    const int fhalf = tid >> 7;          // 0: even frames, 1: odd frames

    const fx4* xb = reinterpret_cast<const fx4*>(x) + (size_t)b * (L_ * D_ / 4);
    fx4* o = reinterpret_cast<fx4*>(out);

    #pragma unroll
    for (int c = 0; c < 2; ++c) {
        const int chunk = blockIdx.x * 2 + c;         // 32-frame chunk
        fx4* ob = o + (size_t)chunk * 32 * 128;       // 32 frames x 128 slots

        int prev = -2;                                // != any id and != -1
        fx4 vv = {0.f, 0.f, 0.f, 0.f};
        #pragma unroll
        for (int i2 = 0; i2 < 16; ++i2) {
            const int fi = 2 * i2 + fhalf;            // frame within chunk
            const int id = ids[c * 32 + fi];          // broadcast from LDS
            if (id != prev) {                         // wave-uniform branch
                if (id >= 0) vv = xb[id * 128 + slot]; // token read (deduped)
                else         vv = (fx4){0.f, 0.f, 0.f, 0.f};
                prev = id;
            }
            __builtin_nontemporal_store(vv, &ob[fi * 128 + slot]);
        }
    }
}

extern "C" void kernel_launch(void* const* d_in, const int* in_sizes, int n_in,
                              void* d_out, int out_size, void* d_ws, size_t ws_size,
                              hipStream_t stream) {
    const float* x = (const float*)d_in[0];
    const int* dur = (const int*)d_in[1];
    // d_in[2] is max_len (== 4096), compile-time constant here.
    float* out = (float*)d_out;

    lr_fused<<<2048, 256, 0, stream>>>(x, dur, out);
}

// Round 12
// 58.701 us; speedup vs baseline: 1.0936x; 1.0338x over previous
//
#include <hip/hip_runtime.h>

// LengthRegulator: B=32, L=1024, D=512, T=max_len=4096
// out[b,t,:] = x[b, searchsorted(cumsum(dur[b]), t, 'right'), :], zero for t >= total.
//
// SINGLE fused kernel, 1024 blocks x 512 threads (one round, 4 blocks/CU,
// 2048 threads/CU). Block owns 128 consecutive frames of row b (= 256 KB of
// writes, identical for every block).
// Prologue: int2 dur read (4 KB/row, L2-broadcast across 32 blocks/row),
//           512-thread x2 shfl scan -> cum in LDS, 128 threads binary-search
//           the block's 128 frame->token ids. (Half the redundant prologues
//           of the 2048-block version.)
// Main loop: 4 chunks x 32 frames, one 128-thread quad each; sequential-frame
//           walk with wave-uniform read dedup (token read ~once), contiguous
//           1 KB/wave NT stores, pad frames (-1) write zeros.

#define B_ 32
#define L_ 1024
#define D_ 512
#define T_ 4096

typedef float fx4 __attribute__((ext_vector_type(4)));

__global__ __launch_bounds__(512) void lr_fused(const float* __restrict__ x,
                                                const int* __restrict__ dur,
                                                float* __restrict__ out) {
    __shared__ int cum[L_];              // row cumulative sums (4 KB)
    __shared__ int wsum[8];              // 8 waves of 64
    __shared__ int ids[128];             // this block's 128 frame ids
    const int tid = threadIdx.x;
    const int b = blockIdx.x >> 5;       // 32 blocks per row
    const int f0 = (blockIdx.x & 31) * 128;

    // ---- prologue: scan this row's durations into cum (LDS) ----
    int2 dv = reinterpret_cast<const int2*>(dur + b * L_)[tid];
    const int a0 = max(dv.x, 0), a1 = max(dv.y, 0);
    const int tsum = a0 + a1;

    int v = tsum;
    const int lane = tid & 63;
    #pragma unroll
    for (int off = 1; off < 64; off <<= 1) {
        int n = __shfl_up(v, off, 64);
        if (lane >= off) v += n;
    }
    const int wv = tid >> 6;             // wave index 0..7
    if (lane == 63) wsum[wv] = v;
    __syncthreads();
    int woff = 0;
    #pragma unroll
    for (int w = 0; w < 7; ++w)
        if (w < wv) woff += wsum[w];
    const int incl = v + woff;
    cum[2 * tid + 0] = incl - a1;
    cum[2 * tid + 1] = incl;
    __syncthreads();

    // ---- resolve this block's 128 frame ids (10-step LDS binary search) ----
    if (tid < 128) {
        const int t = f0 + tid;
        int idx = -1;                    // -1 => zero-pad frame
        if (t < cum[L_ - 1]) {
            idx = 0;                     // searchsorted(cum, t, 'right')
            #pragma unroll
            for (int s = 512; s > 0; s >>= 1)
                if (cum[idx + s - 1] <= t) idx += s;
        }
        ids[tid] = idx;
    }
    __syncthreads();

    // ---- main loop: quad q handles chunk q (32 sequential frames) ----
    const int quad = tid >> 7;           // 0..3
    const int slot = tid & 127;          // float4 slot within frame

    const fx4* xb = reinterpret_cast<const fx4*>(x) + (size_t)b * (L_ * D_ / 4);
    // global frame base: b*T_ + f0 == blockIdx.x * 128
    fx4* ob = reinterpret_cast<fx4*>(out) +
              ((size_t)blockIdx.x * 128 + quad * 32) * 128;

    int prev = -2;                       // != any id and != -1
    fx4 vv = {0.f, 0.f, 0.f, 0.f};
    #pragma unroll
    for (int fi = 0; fi < 32; ++fi) {
        const int id = ids[quad * 32 + fi];           // broadcast from LDS
        if (id != prev) {                             // wave-uniform branch
            if (id >= 0) vv = xb[id * 128 + slot];    // token read (deduped)
            else         vv = (fx4){0.f, 0.f, 0.f, 0.f};
            prev = id;
        }
        __builtin_nontemporal_store(vv, &ob[fi * 128 + slot]);
    }
}

extern "C" void kernel_launch(void* const* d_in, const int* in_sizes, int n_in,
                              void* d_out, int out_size, void* d_ws, size_t ws_size,
                              hipStream_t stream) {
    const float* x = (const float*)d_in[0];
    const int* dur = (const int*)d_in[1];
    // d_in[2] is max_len (== 4096), compile-time constant here.
    float* out = (float*)d_out;

    lr_fused<<<1024, 512, 0, stream>>>(x, dur, out);
}